// Round 1
// baseline (2500.163 us; speedup 1.0000x reference)
//
#include <hip/hip_runtime.h>

#define N_NODES 50000
#define N_EDGES 1600000
#define HIDDEN  128
#define HEADS   8
#define HEAD_DIM 16

// Workspace layout (floats):
//  [0, 50000)                      deg_out -> norm_out (in place)
//  [50000, 100000)                 deg_in  -> norm_in
//  [100000, 500000)                z accumulator (N*HEADS)
//  [500000, 500000+6.4M)           agg (N x 128)
//  [6.9M, 13.3M)                   Q
//  [13.3M, 19.7M)                  K
//  [19.7M, 26.1M)                  V
#define OFF_DEGO  0
#define OFF_DEGI  50000
#define OFF_Z     100000
#define OFF_AGG   500000
#define OFF_Q     6900000
#define OFF_K     13300000
#define OFF_V     19700000

__global__ __launch_bounds__(256) void k_degree(const int* __restrict__ src,
                                                const int* __restrict__ dst,
                                                float* deg_out, float* deg_in) {
    int e = blockIdx.x * 256 + threadIdx.x;
    if (e < N_EDGES) {
        atomicAdd(&deg_out[src[e]], 1.0f);
        atomicAdd(&deg_in[dst[e]], 1.0f);
    }
}

__global__ __launch_bounds__(256) void k_norm(float* deg_out, float* deg_in) {
    int i = blockIdx.x * 256 + threadIdx.x;
    if (i < N_NODES) {
        deg_out[i] = rsqrtf(fmaxf(deg_out[i], 1.0f));
        deg_in[i]  = rsqrtf(fmaxf(deg_in[i], 1.0f));
    }
}

// agg[dst] += h[src] * norm_out[src]; 2 edges per 256-thread block (128 lanes/edge)
__global__ __launch_bounds__(256) void k_agg(const int* __restrict__ src,
                                             const int* __restrict__ dst,
                                             const float* __restrict__ h,
                                             const float* __restrict__ norm_out,
                                             float* __restrict__ agg) {
    int e = blockIdx.x * 2 + (threadIdx.x >> 7);
    if (e >= N_EDGES) return;
    int j = threadIdx.x & 127;
    int s = src[e], d = dst[e];
    float no = norm_out[s];
    atomicAdd(&agg[(size_t)d * 128 + j], h[(size_t)s * 128 + j] * no);
}

// out = relu( (agg * norm_in[:,None]) @ W + b ), one of Q/K/V per blockIdx.y,
// 64-col panel per blockIdx.z. Block = 128 threads, 32 rows x 64 cols tile,
// 4x4 accumulators per thread.
__global__ __launch_bounds__(128) void k_qkv(
    const float* __restrict__ agg, const float* __restrict__ norm_in,
    const float* __restrict__ WQ, const float* __restrict__ bQ,
    const float* __restrict__ WK, const float* __restrict__ bK,
    const float* __restrict__ WV, const float* __restrict__ bV,
    float* __restrict__ Q, float* __restrict__ K, float* __restrict__ V)
{
    const float* W; const float* bias; float* out;
    if (blockIdx.y == 0)      { W = WQ; bias = bQ; out = Q; }
    else if (blockIdx.y == 1) { W = WK; bias = bK; out = K; }
    else                      { W = WV; bias = bV; out = V; }
    const int row0 = blockIdx.x * 32;
    const int col0 = blockIdx.z * 64;

    __shared__ float sW[128][64];  // [k][c], 32 KB
    __shared__ float sA[128][36];  // [k][r] transposed + pad, 18 KB

    const int t = threadIdx.x;  // 0..127
    // stage W panel: 128x64 floats = 2048 float4, 16 per thread
    {
        const float* Wp = W + col0;
        for (int i = t; i < 128 * 16; i += 128) {
            int k = i >> 4, c4 = (i & 15) << 2;
            float4 w = *(const float4*)(Wp + k * 128 + c4);
            *(float4*)(&sW[k][c4]) = w;
        }
        // stage A tile transposed, scaled by norm_in[row]
        for (int i = t; i < 32 * 32; i += 128) {
            int r = i >> 5, k4 = (i & 31) << 2;
            int row = row0 + r;
            float4 a = make_float4(0.f, 0.f, 0.f, 0.f);
            float ni = 0.f;
            if (row < N_NODES) {
                a = *(const float4*)(agg + (size_t)row * 128 + k4);
                ni = norm_in[row];
            }
            sA[k4 + 0][r] = a.x * ni;
            sA[k4 + 1][r] = a.y * ni;
            sA[k4 + 2][r] = a.z * ni;
            sA[k4 + 3][r] = a.w * ni;
        }
    }
    __syncthreads();

    const int rq = (t & 7) << 2;   // 0..28
    const int cq = (t >> 3) << 2;  // 0..60
    float acc[4][4] = {};
    for (int k = 0; k < 128; ++k) {
        float4 a = *(const float4*)(&sA[k][rq]);
        float4 w = *(const float4*)(&sW[k][cq]);
        acc[0][0] += a.x * w.x; acc[0][1] += a.x * w.y; acc[0][2] += a.x * w.z; acc[0][3] += a.x * w.w;
        acc[1][0] += a.y * w.x; acc[1][1] += a.y * w.y; acc[1][2] += a.y * w.z; acc[1][3] += a.y * w.w;
        acc[2][0] += a.z * w.x; acc[2][1] += a.z * w.y; acc[2][2] += a.z * w.z; acc[2][3] += a.z * w.w;
        acc[3][0] += a.w * w.x; acc[3][1] += a.w * w.y; acc[3][2] += a.w * w.z; acc[3][3] += a.w * w.w;
    }

    float4 bv = *(const float4*)(bias + col0 + cq);
    for (int i = 0; i < 4; ++i) {
        int row = row0 + rq + i;
        if (row < N_NODES) {
            float4 o;
            o.x = fmaxf(acc[i][0] + bv.x, 0.f);
            o.y = fmaxf(acc[i][1] + bv.y, 0.f);
            o.z = fmaxf(acc[i][2] + bv.z, 0.f);
            o.w = fmaxf(acc[i][3] + bv.w, 0.f);
            *(float4*)(out + (size_t)row * 128 + col0 + cq) = o;
        }
    }
}

// per-edge attention: one wave per edge (4 edges per 256-thread block)
__global__ __launch_bounds__(256) void k_attn(
    const int* __restrict__ src, const int* __restrict__ dst,
    const float* __restrict__ Q, const float* __restrict__ K,
    const float* __restrict__ V,
    float* __restrict__ out, float* __restrict__ z)
{
    int e = blockIdx.x * 4 + (threadIdx.x >> 6);
    if (e >= N_EDGES) return;
    int lane = threadIdx.x & 63;
    int s = src[e], d = dst[e];
    float2 k2 = *(const float2*)(K + (size_t)s * 128 + lane * 2);
    float2 q2 = *(const float2*)(Q + (size_t)d * 128 + lane * 2);
    float p = k2.x * q2.x + k2.y * q2.y;
    // reduce within 8-lane groups: head = lane>>3 (dims 2*lane, 2*lane+1 -> head (2*lane)/16)
    p += __shfl_xor(p, 1);
    p += __shfl_xor(p, 2);
    p += __shfl_xor(p, 4);
    float score = __expf(fminf(fmaxf(p * 0.25f, -10.f), 10.f));
    if ((lane & 7) == 0) atomicAdd(&z[(size_t)d * 8 + (lane >> 3)], score);
    float2 v2 = *(const float2*)(V + (size_t)s * 128 + lane * 2);
    atomicAdd(out + (size_t)d * 128 + lane * 2,     v2.x * score);
    atomicAdd(out + (size_t)d * 128 + lane * 2 + 1, v2.y * score);
}

__global__ __launch_bounds__(256) void k_final(float* __restrict__ out,
                                               const float* __restrict__ z) {
    int i = blockIdx.x * 256 + threadIdx.x;
    if (i < N_NODES * 128) {
        int n = i >> 7, j = i & 127;
        out[i] = out[i] / (z[n * 8 + (j >> 4)] + 1e-6f);
    }
}

extern "C" void kernel_launch(void* const* d_in, const int* in_sizes, int n_in,
                              void* d_out, int out_size, void* d_ws, size_t ws_size,
                              hipStream_t stream) {
    const float* h   = (const float*)d_in[0];
    const float* WQ  = (const float*)d_in[1];
    const float* bQ  = (const float*)d_in[2];
    const float* WK  = (const float*)d_in[3];
    const float* bK  = (const float*)d_in[4];
    const float* WV  = (const float*)d_in[5];
    const float* bV  = (const float*)d_in[6];
    const int*   src = (const int*)d_in[7];
    const int*   dst = (const int*)d_in[8];
    float* out = (float*)d_out;
    float* ws  = (float*)d_ws;

    float* deg_out = ws + OFF_DEGO;
    float* deg_in  = ws + OFF_DEGI;
    float* z       = ws + OFF_Z;
    float* agg     = ws + OFF_AGG;
    float* Q       = ws + OFF_Q;
    float* K       = ws + OFF_K;
    float* V       = ws + OFF_V;

    // zero deg_out, deg_in, z, agg (contiguous: first OFF_AGG+6.4M floats) and d_out
    hipMemsetAsync(ws, 0, (size_t)(OFF_AGG + N_NODES * 128) * sizeof(float), stream);
    hipMemsetAsync(d_out, 0, (size_t)N_NODES * 128 * sizeof(float), stream);

    k_degree<<<(N_EDGES + 255) / 256, 256, 0, stream>>>(src, dst, deg_out, deg_in);
    k_norm<<<(N_NODES + 255) / 256, 256, 0, stream>>>(deg_out, deg_in);
    k_agg<<<N_EDGES / 2, 256, 0, stream>>>(src, dst, h, deg_out, agg);
    dim3 g_qkv((N_NODES + 31) / 32, 3, 2);
    k_qkv<<<g_qkv, 128, 0, stream>>>(agg, deg_in, WQ, bQ, WK, bK, WV, bV, Q, K, V);
    k_attn<<<N_EDGES / 4, 256, 0, stream>>>(src, dst, Q, K, V, out, z);
    k_final<<<(N_NODES * 128 + 255) / 256, 256, 0, stream>>>(out, z);
}

// Round 2
// 915.681 us; speedup vs baseline: 2.7304x; 2.7304x over previous
//
#include <hip/hip_runtime.h>

#define N_NODES 50000
#define N_EDGES 1600000
#define NB_SCAN 196   // ceil(50000/256)

// Workspace element offsets (4-byte units). Peak usage ~84.6 MB.
#define O_CNTO   0         // int[50000]  out-degree counts
#define O_CNTI   50000     // int[50000]  in-degree counts
#define O_NRMO   100000    // f32[50000]  rsqrt(max(deg_out,1))
#define O_NRMI   150000    // f32[50000]  rsqrt(max(deg_in,1))
#define O_ROW    200000    // int[50000]  CSR row starts (by dst)
#define O_CUR    250000    // int[50000]  fill cursors
#define O_BSUM   300000    // int[256]    scan block sums
#define O_ESRC   350000    // int[1.6M]   src node per CSR slot
#define O_AGG    1950000   // f32[50000*128] agg; later overwritten by Q in-place
#define O_K      8350000   // f32[50000*128]
#define O_V      14750000  // f32[50000*128]

__global__ __launch_bounds__(256) void k_degree(const int* __restrict__ src,
                                                const int* __restrict__ dst,
                                                int* cnt_out, int* cnt_in) {
    int e = blockIdx.x * 256 + threadIdx.x;
    if (e < N_EDGES) {
        atomicAdd(&cnt_out[src[e]], 1);
        atomicAdd(&cnt_in[dst[e]], 1);
    }
}

__global__ __launch_bounds__(256) void k_norm(const int* __restrict__ cnt_out,
                                              const int* __restrict__ cnt_in,
                                              float* norm_out, float* norm_in) {
    int i = blockIdx.x * 256 + threadIdx.x;
    if (i < N_NODES) {
        norm_out[i] = rsqrtf(fmaxf((float)cnt_out[i], 1.0f));
        norm_in[i]  = rsqrtf(fmaxf((float)cnt_in[i], 1.0f));
    }
}

// --- exclusive scan of cnt_in -> row_start (3 kernels) ---
__global__ __launch_bounds__(256) void k_scan1(const int* __restrict__ cnt_in,
                                               int* row_start, int* bsum) {
    __shared__ int s[256];
    int t = threadIdx.x;
    int i = blockIdx.x * 256 + t;
    int x = (i < N_NODES) ? cnt_in[i] : 0;
    s[t] = x;
    __syncthreads();
    for (int off = 1; off < 256; off <<= 1) {
        int v = (t >= off) ? s[t - off] : 0;
        __syncthreads();
        s[t] += v;
        __syncthreads();
    }
    if (i < N_NODES) row_start[i] = s[t] - x;   // exclusive
    if (t == 255) bsum[blockIdx.x] = s[255];
}

__global__ __launch_bounds__(256) void k_scan2(int* bsum) {
    __shared__ int s[256];
    int t = threadIdx.x;
    int x = (t < NB_SCAN) ? bsum[t] : 0;
    s[t] = x;
    __syncthreads();
    for (int off = 1; off < 256; off <<= 1) {
        int v = (t >= off) ? s[t - off] : 0;
        __syncthreads();
        s[t] += v;
        __syncthreads();
    }
    if (t < NB_SCAN) bsum[t] = s[t] - x;        // exclusive over block sums
}

__global__ __launch_bounds__(256) void k_scan3(int* row_start, const int* __restrict__ bsum,
                                               int* cursor) {
    int i = blockIdx.x * 256 + threadIdx.x;
    if (i < N_NODES) {
        int r = row_start[i] + bsum[blockIdx.x];
        row_start[i] = r;
        cursor[i] = r;
    }
}

__global__ __launch_bounds__(256) void k_scatter(const int* __restrict__ src,
                                                 const int* __restrict__ dst,
                                                 int* cursor, int* __restrict__ edge_src) {
    int e = blockIdx.x * 256 + threadIdx.x;
    if (e < N_EDGES) {
        int pos = atomicAdd(&cursor[dst[e]], 1);
        edge_src[pos] = src[e];
    }
}

// agg[n] = norm_in[n] * sum_{e: dst=n} h[src_e] * norm_out[src_e]
// one wave per node, 4 nodes per block; lane owns dims [2*lane, 2*lane+1]
__global__ __launch_bounds__(256) void k_agg_csr(
    const int* __restrict__ row_start, const int* __restrict__ cnt_in,
    const int* __restrict__ edge_src,
    const float* __restrict__ h, const float* __restrict__ norm_out,
    const float* __restrict__ norm_in, float* __restrict__ agg)
{
    int n = blockIdx.x * 4 + (threadIdx.x >> 6);
    int lane = threadIdx.x & 63;
    int beg = row_start[n], end = beg + cnt_in[n];
    float ax = 0.f, ay = 0.f;
    for (int i = beg; i < end; ++i) {
        int s = edge_src[i];
        float no = norm_out[s];
        float2 hv = *(const float2*)(h + (size_t)s * 128 + lane * 2);
        ax += hv.x * no;
        ay += hv.y * no;
    }
    float ni = norm_in[n];
    float2 o; o.x = ax * ni; o.y = ay * ni;
    *(float2*)(agg + (size_t)n * 128 + lane * 2) = o;
}

// K,V GEMM: out = relu(agg @ W + b); y selects K/V, z selects 64-col panel.
__global__ __launch_bounds__(128) void k_kv(
    const float* __restrict__ agg,
    const float* __restrict__ WK, const float* __restrict__ bK,
    const float* __restrict__ WV, const float* __restrict__ bV,
    float* __restrict__ K, float* __restrict__ V)
{
    const float* W; const float* bias; float* out;
    if (blockIdx.y == 0) { W = WK; bias = bK; out = K; }
    else                 { W = WV; bias = bV; out = V; }
    const int row0 = blockIdx.x * 32;
    const int col0 = blockIdx.z * 64;

    __shared__ float sW[128][64];
    __shared__ float sA[128][36];

    const int t = threadIdx.x;
    {
        const float* Wp = W + col0;
        for (int i = t; i < 128 * 16; i += 128) {
            int k = i >> 4, c4 = (i & 15) << 2;
            *(float4*)(&sW[k][c4]) = *(const float4*)(Wp + k * 128 + c4);
        }
        for (int i = t; i < 32 * 32; i += 128) {
            int r = i >> 5, k4 = (i & 31) << 2;
            int row = row0 + r;
            float4 a = make_float4(0.f, 0.f, 0.f, 0.f);
            if (row < N_NODES) a = *(const float4*)(agg + (size_t)row * 128 + k4);
            sA[k4 + 0][r] = a.x; sA[k4 + 1][r] = a.y;
            sA[k4 + 2][r] = a.z; sA[k4 + 3][r] = a.w;
        }
    }
    __syncthreads();

    const int rq = (t & 7) << 2;
    const int cq = (t >> 3) << 2;
    float acc[4][4] = {};
    for (int k = 0; k < 128; ++k) {
        float4 a = *(const float4*)(&sA[k][rq]);
        float4 w = *(const float4*)(&sW[k][cq]);
        acc[0][0] += a.x * w.x; acc[0][1] += a.x * w.y; acc[0][2] += a.x * w.z; acc[0][3] += a.x * w.w;
        acc[1][0] += a.y * w.x; acc[1][1] += a.y * w.y; acc[1][2] += a.y * w.z; acc[1][3] += a.y * w.w;
        acc[2][0] += a.z * w.x; acc[2][1] += a.z * w.y; acc[2][2] += a.z * w.z; acc[2][3] += a.z * w.w;
        acc[3][0] += a.w * w.x; acc[3][1] += a.w * w.y; acc[3][2] += a.w * w.z; acc[3][3] += a.w * w.w;
    }

    float4 bv = *(const float4*)(bias + col0 + cq);
    for (int i = 0; i < 4; ++i) {
        int row = row0 + rq + i;
        if (row < N_NODES) {
            float4 o;
            o.x = fmaxf(acc[i][0] + bv.x, 0.f);
            o.y = fmaxf(acc[i][1] + bv.y, 0.f);
            o.z = fmaxf(acc[i][2] + bv.z, 0.f);
            o.w = fmaxf(acc[i][3] + bv.w, 0.f);
            *(float4*)(out + (size_t)row * 128 + col0 + cq) = o;
        }
    }
}

// Q GEMM in-place over agg: block = 32 rows x 128 cols, 256 threads.
// A tile staged to LDS first, so overwriting agg with Q is safe.
__global__ __launch_bounds__(256) void k_q_inplace(
    float* __restrict__ agg, const float* __restrict__ WQ,
    const float* __restrict__ bQ)
{
    const int row0 = blockIdx.x * 32;
    __shared__ float sA[128][36];   // [k][r]
    __shared__ float sW[32][128];   // k-chunk of W

    const int t = threadIdx.x;
    for (int i = t; i < 32 * 32; i += 256) {
        int r = i >> 5, k4 = (i & 31) << 2;
        int row = row0 + r;
        float4 a = make_float4(0.f, 0.f, 0.f, 0.f);
        if (row < N_NODES) a = *(const float4*)(agg + (size_t)row * 128 + k4);
        sA[k4 + 0][r] = a.x; sA[k4 + 1][r] = a.y;
        sA[k4 + 2][r] = a.z; sA[k4 + 3][r] = a.w;
    }

    const int rq = (t & 7) << 2;    // 0..28
    const int cq = (t >> 3) << 2;   // 0..124
    float acc[4][4] = {};

    for (int kc = 0; kc < 128; kc += 32) {
        __syncthreads();
        for (int i = t; i < 1024; i += 256) {
            int k = i >> 5, c4 = (i & 31) << 2;
            *(float4*)(&sW[k][c4]) = *(const float4*)(WQ + (size_t)(kc + k) * 128 + c4);
        }
        __syncthreads();
        for (int kk = 0; kk < 32; ++kk) {
            float4 a = *(const float4*)(&sA[kc + kk][rq]);
            float4 w = *(const float4*)(&sW[kk][cq]);
            acc[0][0] += a.x * w.x; acc[0][1] += a.x * w.y; acc[0][2] += a.x * w.z; acc[0][3] += a.x * w.w;
            acc[1][0] += a.y * w.x; acc[1][1] += a.y * w.y; acc[1][2] += a.y * w.z; acc[1][3] += a.y * w.w;
            acc[2][0] += a.z * w.x; acc[2][1] += a.z * w.y; acc[2][2] += a.z * w.z; acc[2][3] += a.z * w.w;
            acc[3][0] += a.w * w.x; acc[3][1] += a.w * w.y; acc[3][2] += a.w * w.z; acc[3][3] += a.w * w.w;
        }
    }

    float4 bv = *(const float4*)(bQ + cq);
    for (int i = 0; i < 4; ++i) {
        int row = row0 + rq + i;
        if (row < N_NODES) {
            float4 o;
            o.x = fmaxf(acc[i][0] + bv.x, 0.f);
            o.y = fmaxf(acc[i][1] + bv.y, 0.f);
            o.z = fmaxf(acc[i][2] + bv.z, 0.f);
            o.w = fmaxf(acc[i][3] + bv.w, 0.f);
            *(float4*)(agg + (size_t)row * 128 + cq) = o;
        }
    }
}

// Attention gather: one wave per node; lane owns dims [2*lane, 2*lane+1],
// head = lane>>3. Q[dst] register-resident; fused z-normalization.
__global__ __launch_bounds__(256) void k_attn_csr(
    const int* __restrict__ row_start, const int* __restrict__ cnt_in,
    const int* __restrict__ edge_src,
    const float* __restrict__ Q, const float* __restrict__ K,
    const float* __restrict__ V, float* __restrict__ out)
{
    int n = blockIdx.x * 4 + (threadIdx.x >> 6);
    int lane = threadIdx.x & 63;
    int beg = row_start[n], end = beg + cnt_in[n];

    float2 q2 = *(const float2*)(Q + (size_t)n * 128 + lane * 2);
    float ax = 0.f, ay = 0.f, zacc = 0.f;

    for (int i = beg; i < end; ++i) {
        int s = edge_src[i];
        float2 k2 = *(const float2*)(K + (size_t)s * 128 + lane * 2);
        float2 v2 = *(const float2*)(V + (size_t)s * 128 + lane * 2);
        float p = k2.x * q2.x + k2.y * q2.y;
        p += __shfl_xor(p, 1);
        p += __shfl_xor(p, 2);
        p += __shfl_xor(p, 4);
        float score = __expf(fminf(fmaxf(p * 0.25f, -10.f), 10.f));
        ax += v2.x * score;
        ay += v2.y * score;
        zacc += score;   // all 8 lanes of a head hold the same score
    }

    float inv = 1.0f / (zacc + 1e-6f);
    float2 o; o.x = ax * inv; o.y = ay * inv;
    *(float2*)(out + (size_t)n * 128 + lane * 2) = o;
}

extern "C" void kernel_launch(void* const* d_in, const int* in_sizes, int n_in,
                              void* d_out, int out_size, void* d_ws, size_t ws_size,
                              hipStream_t stream) {
    const float* h   = (const float*)d_in[0];
    const float* WQ  = (const float*)d_in[1];
    const float* bQ  = (const float*)d_in[2];
    const float* WK  = (const float*)d_in[3];
    const float* bK  = (const float*)d_in[4];
    const float* WV  = (const float*)d_in[5];
    const float* bV  = (const float*)d_in[6];
    const int*   src = (const int*)d_in[7];
    const int*   dst = (const int*)d_in[8];
    float* out = (float*)d_out;
    float* ws  = (float*)d_ws;
    int*   wsi = (int*)d_ws;

    int*   cnt_out  = wsi + O_CNTO;
    int*   cnt_in   = wsi + O_CNTI;
    float* norm_out = ws  + O_NRMO;
    float* norm_in  = ws  + O_NRMI;
    int*   row_st   = wsi + O_ROW;
    int*   cursor   = wsi + O_CUR;
    int*   bsum     = wsi + O_BSUM;
    int*   edge_src = wsi + O_ESRC;
    float* agg      = ws  + O_AGG;   // becomes Q in-place
    float* Kb       = ws  + O_K;
    float* Vb       = ws  + O_V;

    // zero only the degree counters
    hipMemsetAsync(wsi, 0, 2 * N_NODES * sizeof(int), stream);

    k_degree<<<N_EDGES / 256, 256, 0, stream>>>(src, dst, cnt_out, cnt_in);
    k_norm<<<NB_SCAN, 256, 0, stream>>>(cnt_out, cnt_in, norm_out, norm_in);
    k_scan1<<<NB_SCAN, 256, 0, stream>>>(cnt_in, row_st, bsum);
    k_scan2<<<1, 256, 0, stream>>>(bsum);
    k_scan3<<<NB_SCAN, 256, 0, stream>>>(row_st, bsum, cursor);
    k_scatter<<<N_EDGES / 256, 256, 0, stream>>>(src, dst, cursor, edge_src);

    k_agg_csr<<<N_NODES / 4, 256, 0, stream>>>(row_st, cnt_in, edge_src,
                                               h, norm_out, norm_in, agg);

    dim3 g_kv((N_NODES + 31) / 32, 2, 2);
    k_kv<<<g_kv, 128, 0, stream>>>(agg, WK, bK, WV, bV, Kb, Vb);
    k_q_inplace<<<(N_NODES + 31) / 32, 256, 0, stream>>>(agg, WQ, bQ);

    k_attn_csr<<<N_NODES / 4, 256, 0, stream>>>(row_st, cnt_in, edge_src,
                                                agg, Kb, Vb, out);
}

// Round 3
// 746.211 us; speedup vs baseline: 3.3505x; 1.2271x over previous
//
#include <hip/hip_runtime.h>

#define N_NODES 50000
#define N_EDGES 1600000
#define NB_SCAN 196   // ceil(50000/256)

// Workspace element offsets (4-byte units).
#define O_CNTO   0         // int[50000]  out-degree counts
#define O_CNTI   50000     // int[50000]  in-degree counts
#define O_NRMO   100000    // f32[50000]  rsqrt(max(deg_out,1))
#define O_NRMI   150000    // f32[50000]  rsqrt(max(deg_in,1))
#define O_ROW    200000    // int[50000]  CSR row starts (by dst)
#define O_CUR    250000    // int[50000]  fill cursors
#define O_BSUM   300000    // int[256]    scan block sums
#define O_ESRC   350000    // int[1.6M]   src node per CSR slot
#define O_AGG    1950000   // f32[50000*128] agg; later overwritten by Q in-place
#define O_K      8350000   // bf16[50000*128] (12.8 MB)
#define O_V      11550000  // bf16[50000*128]

typedef unsigned int uint;

__device__ __forceinline__ uint f2bf2(float a, float b) {
    uint ua = __float_as_uint(a); ua = (ua + 0x7fffu + ((ua >> 16) & 1u)) >> 16;
    uint ub = __float_as_uint(b); ub = (ub + 0x7fffu + ((ub >> 16) & 1u)) >> 16;
    return ua | (ub << 16);
}

__global__ __launch_bounds__(256) void k_degree(const int* __restrict__ src,
                                                const int* __restrict__ dst,
                                                int* cnt_out, int* cnt_in) {
    int e = blockIdx.x * 256 + threadIdx.x;
    if (e < N_EDGES) {
        atomicAdd(&cnt_out[src[e]], 1);
        atomicAdd(&cnt_in[dst[e]], 1);
    }
}

// scan1 + norm computation fused
__global__ __launch_bounds__(256) void k_scan1(const int* __restrict__ cnt_in,
                                               const int* __restrict__ cnt_out,
                                               int* row_start, int* bsum,
                                               float* norm_out, float* norm_in) {
    __shared__ int s[256];
    int t = threadIdx.x;
    int i = blockIdx.x * 256 + t;
    int x = (i < N_NODES) ? cnt_in[i] : 0;
    s[t] = x;
    if (i < N_NODES) {
        norm_in[i]  = rsqrtf(fmaxf((float)x, 1.0f));
        norm_out[i] = rsqrtf(fmaxf((float)cnt_out[i], 1.0f));
    }
    __syncthreads();
    for (int off = 1; off < 256; off <<= 1) {
        int v = (t >= off) ? s[t - off] : 0;
        __syncthreads();
        s[t] += v;
        __syncthreads();
    }
    if (i < N_NODES) row_start[i] = s[t] - x;   // exclusive
    if (t == 255) bsum[blockIdx.x] = s[255];
}

__global__ __launch_bounds__(256) void k_scan2(int* bsum) {
    __shared__ int s[256];
    int t = threadIdx.x;
    int x = (t < NB_SCAN) ? bsum[t] : 0;
    s[t] = x;
    __syncthreads();
    for (int off = 1; off < 256; off <<= 1) {
        int v = (t >= off) ? s[t - off] : 0;
        __syncthreads();
        s[t] += v;
        __syncthreads();
    }
    if (t < NB_SCAN) bsum[t] = s[t] - x;        // exclusive over block sums
}

__global__ __launch_bounds__(256) void k_scan3(int* row_start, const int* __restrict__ bsum,
                                               int* cursor) {
    int i = blockIdx.x * 256 + threadIdx.x;
    if (i < N_NODES) {
        int r = row_start[i] + bsum[blockIdx.x];
        row_start[i] = r;
        cursor[i] = r;
    }
}

__global__ __launch_bounds__(256) void k_scatter(const int* __restrict__ src,
                                                 const int* __restrict__ dst,
                                                 int* cursor, int* __restrict__ edge_src) {
    int e = blockIdx.x * 256 + threadIdx.x;
    if (e < N_EDGES) {
        int pos = atomicAdd(&cursor[dst[e]], 1);
        edge_src[pos] = src[e];
    }
}

// agg[n] = norm_in[n] * sum_{e: dst=n} h[src_e] * norm_out[src_e]
// one wave per node, 4 nodes per block; lane owns dims [2*lane, 2*lane+1]
// unrolled x2 for load-latency overlap
__global__ __launch_bounds__(256) void k_agg_csr(
    const int* __restrict__ row_start, const int* __restrict__ cnt_in,
    const int* __restrict__ edge_src,
    const float* __restrict__ h, const float* __restrict__ norm_out,
    const float* __restrict__ norm_in, float* __restrict__ agg)
{
    int n = blockIdx.x * 4 + (threadIdx.x >> 6);
    int lane = threadIdx.x & 63;
    int beg = row_start[n], end = beg + cnt_in[n];
    float ax = 0.f, ay = 0.f;
    int i = beg;
    for (; i + 2 <= end; i += 2) {
        int s0 = edge_src[i];
        int s1 = edge_src[i + 1];
        float no0 = norm_out[s0];
        float no1 = norm_out[s1];
        float2 h0 = *(const float2*)(h + ((size_t)s0 << 7) + (lane << 1));
        float2 h1 = *(const float2*)(h + ((size_t)s1 << 7) + (lane << 1));
        ax += h0.x * no0; ay += h0.y * no0;
        ax += h1.x * no1; ay += h1.y * no1;
    }
    if (i < end) {
        int s = edge_src[i];
        float no = norm_out[s];
        float2 hv = *(const float2*)(h + ((size_t)s << 7) + (lane << 1));
        ax += hv.x * no; ay += hv.y * no;
    }
    float ni = norm_in[n];
    float2 o; o.x = ax * ni; o.y = ay * ni;
    *(float2*)(agg + ((size_t)n << 7) + (lane << 1)) = o;
}

// K,V GEMM: out = relu(agg @ W + b) stored as bf16; y selects K/V, z selects 64-col panel.
__global__ __launch_bounds__(128) void k_kv(
    const float* __restrict__ agg,
    const float* __restrict__ WK, const float* __restrict__ bK,
    const float* __restrict__ WV, const float* __restrict__ bV,
    unsigned short* __restrict__ K, unsigned short* __restrict__ V)
{
    const float* W; const float* bias; unsigned short* out;
    if (blockIdx.y == 0) { W = WK; bias = bK; out = K; }
    else                 { W = WV; bias = bV; out = V; }
    const int row0 = blockIdx.x * 32;
    const int col0 = blockIdx.z * 64;

    __shared__ float sW[128][64];
    __shared__ float sA[128][36];

    const int t = threadIdx.x;
    {
        const float* Wp = W + col0;
        for (int i = t; i < 128 * 16; i += 128) {
            int k = i >> 4, c4 = (i & 15) << 2;
            *(float4*)(&sW[k][c4]) = *(const float4*)(Wp + k * 128 + c4);
        }
        for (int i = t; i < 32 * 32; i += 128) {
            int r = i >> 5, k4 = (i & 31) << 2;
            int row = row0 + r;
            float4 a = make_float4(0.f, 0.f, 0.f, 0.f);
            if (row < N_NODES) a = *(const float4*)(agg + (size_t)row * 128 + k4);
            sA[k4 + 0][r] = a.x; sA[k4 + 1][r] = a.y;
            sA[k4 + 2][r] = a.z; sA[k4 + 3][r] = a.w;
        }
    }
    __syncthreads();

    const int rq = (t & 7) << 2;
    const int cq = (t >> 3) << 2;
    float acc[4][4] = {};
    for (int k = 0; k < 128; ++k) {
        float4 a = *(const float4*)(&sA[k][rq]);
        float4 w = *(const float4*)(&sW[k][cq]);
        acc[0][0] += a.x * w.x; acc[0][1] += a.x * w.y; acc[0][2] += a.x * w.z; acc[0][3] += a.x * w.w;
        acc[1][0] += a.y * w.x; acc[1][1] += a.y * w.y; acc[1][2] += a.y * w.z; acc[1][3] += a.y * w.w;
        acc[2][0] += a.z * w.x; acc[2][1] += a.z * w.y; acc[2][2] += a.z * w.z; acc[2][3] += a.z * w.w;
        acc[3][0] += a.w * w.x; acc[3][1] += a.w * w.y; acc[3][2] += a.w * w.z; acc[3][3] += a.w * w.w;
    }

    float4 bv = *(const float4*)(bias + col0 + cq);
    for (int i = 0; i < 4; ++i) {
        int row = row0 + rq + i;
        if (row < N_NODES) {
            float ox = fmaxf(acc[i][0] + bv.x, 0.f);
            float oy = fmaxf(acc[i][1] + bv.y, 0.f);
            float oz = fmaxf(acc[i][2] + bv.z, 0.f);
            float ow = fmaxf(acc[i][3] + bv.w, 0.f);
            uint2 pk; pk.x = f2bf2(ox, oy); pk.y = f2bf2(oz, ow);
            *(uint2*)(out + (size_t)row * 128 + col0 + cq) = pk;
        }
    }
}

// Q GEMM in-place over agg: block = 32 rows x 128 cols, 256 threads.
__global__ __launch_bounds__(256) void k_q_inplace(
    float* __restrict__ agg, const float* __restrict__ WQ,
    const float* __restrict__ bQ)
{
    const int row0 = blockIdx.x * 32;
    __shared__ float sA[128][36];   // [k][r]
    __shared__ float sW[32][128];   // k-chunk of W

    const int t = threadIdx.x;
    for (int i = t; i < 32 * 32; i += 256) {
        int r = i >> 5, k4 = (i & 31) << 2;
        int row = row0 + r;
        float4 a = make_float4(0.f, 0.f, 0.f, 0.f);
        if (row < N_NODES) a = *(const float4*)(agg + (size_t)row * 128 + k4);
        sA[k4 + 0][r] = a.x; sA[k4 + 1][r] = a.y;
        sA[k4 + 2][r] = a.z; sA[k4 + 3][r] = a.w;
    }

    const int rq = (t & 7) << 2;    // 0..28
    const int cq = (t >> 3) << 2;   // 0..124
    float acc[4][4] = {};

    for (int kc = 0; kc < 128; kc += 32) {
        __syncthreads();
        for (int i = t; i < 1024; i += 256) {
            int k = i >> 5, c4 = (i & 31) << 2;
            *(float4*)(&sW[k][c4]) = *(const float4*)(WQ + (size_t)(kc + k) * 128 + c4);
        }
        __syncthreads();
        for (int kk = 0; kk < 32; ++kk) {
            float4 a = *(const float4*)(&sA[kc + kk][rq]);
            float4 w = *(const float4*)(&sW[kk][cq]);
            acc[0][0] += a.x * w.x; acc[0][1] += a.x * w.y; acc[0][2] += a.x * w.z; acc[0][3] += a.x * w.w;
            acc[1][0] += a.y * w.x; acc[1][1] += a.y * w.y; acc[1][2] += a.y * w.z; acc[1][3] += a.y * w.w;
            acc[2][0] += a.z * w.x; acc[2][1] += a.z * w.y; acc[2][2] += a.z * w.z; acc[2][3] += a.z * w.w;
            acc[3][0] += a.w * w.x; acc[3][1] += a.w * w.y; acc[3][2] += a.w * w.z; acc[3][3] += a.w * w.w;
        }
    }

    float4 bv = *(const float4*)(bQ + cq);
    for (int i = 0; i < 4; ++i) {
        int row = row0 + rq + i;
        if (row < N_NODES) {
            float4 o;
            o.x = fmaxf(acc[i][0] + bv.x, 0.f);
            o.y = fmaxf(acc[i][1] + bv.y, 0.f);
            o.z = fmaxf(acc[i][2] + bv.z, 0.f);
            o.w = fmaxf(acc[i][3] + bv.w, 0.f);
            *(float4*)(agg + (size_t)row * 128 + cq) = o;
        }
    }
}

// Attention gather: one wave per node; lane owns dims [2*lane, 2*lane+1],
// head = lane>>3. K/V are bf16 rows (256 B). Unrolled x2.
__global__ __launch_bounds__(256) void k_attn_csr(
    const int* __restrict__ row_start, const int* __restrict__ cnt_in,
    const int* __restrict__ edge_src,
    const float* __restrict__ Q, const unsigned short* __restrict__ K,
    const unsigned short* __restrict__ V, float* __restrict__ out)
{
    int n = blockIdx.x * 4 + (threadIdx.x >> 6);
    int lane = threadIdx.x & 63;
    int beg = row_start[n], end = beg + cnt_in[n];

    float2 q2 = *(const float2*)(Q + ((size_t)n << 7) + (lane << 1));
    float ax = 0.f, ay = 0.f, zacc = 0.f;

    int i = beg;
    for (; i + 2 <= end; i += 2) {
        int s0 = edge_src[i];
        int s1 = edge_src[i + 1];
        uint ku0 = *(const uint*)(K + ((size_t)s0 << 7) + (lane << 1));
        uint vu0 = *(const uint*)(V + ((size_t)s0 << 7) + (lane << 1));
        uint ku1 = *(const uint*)(K + ((size_t)s1 << 7) + (lane << 1));
        uint vu1 = *(const uint*)(V + ((size_t)s1 << 7) + (lane << 1));

        float p0 = __uint_as_float(ku0 << 16) * q2.x + __uint_as_float(ku0 & 0xffff0000u) * q2.y;
        float p1 = __uint_as_float(ku1 << 16) * q2.x + __uint_as_float(ku1 & 0xffff0000u) * q2.y;
        p0 += __shfl_xor(p0, 1); p1 += __shfl_xor(p1, 1);
        p0 += __shfl_xor(p0, 2); p1 += __shfl_xor(p1, 2);
        p0 += __shfl_xor(p0, 4); p1 += __shfl_xor(p1, 4);
        float sc0 = __expf(fminf(fmaxf(p0 * 0.25f, -10.f), 10.f));
        float sc1 = __expf(fminf(fmaxf(p1 * 0.25f, -10.f), 10.f));
        ax += __uint_as_float(vu0 << 16) * sc0;
        ay += __uint_as_float(vu0 & 0xffff0000u) * sc0;
        ax += __uint_as_float(vu1 << 16) * sc1;
        ay += __uint_as_float(vu1 & 0xffff0000u) * sc1;
        zacc += sc0 + sc1;
    }
    if (i < end) {
        int s = edge_src[i];
        uint ku = *(const uint*)(K + ((size_t)s << 7) + (lane << 1));
        uint vu = *(const uint*)(V + ((size_t)s << 7) + (lane << 1));
        float p = __uint_as_float(ku << 16) * q2.x + __uint_as_float(ku & 0xffff0000u) * q2.y;
        p += __shfl_xor(p, 1);
        p += __shfl_xor(p, 2);
        p += __shfl_xor(p, 4);
        float sc = __expf(fminf(fmaxf(p * 0.25f, -10.f), 10.f));
        ax += __uint_as_float(vu << 16) * sc;
        ay += __uint_as_float(vu & 0xffff0000u) * sc;
        zacc += sc;
    }

    float inv = 1.0f / (zacc + 1e-6f);
    float2 o; o.x = ax * inv; o.y = ay * inv;
    *(float2*)(out + ((size_t)n << 7) + (lane << 1)) = o;
}

extern "C" void kernel_launch(void* const* d_in, const int* in_sizes, int n_in,
                              void* d_out, int out_size, void* d_ws, size_t ws_size,
                              hipStream_t stream) {
    const float* h   = (const float*)d_in[0];
    const float* WQ  = (const float*)d_in[1];
    const float* bQ  = (const float*)d_in[2];
    const float* WK  = (const float*)d_in[3];
    const float* bK  = (const float*)d_in[4];
    const float* WV  = (const float*)d_in[5];
    const float* bV  = (const float*)d_in[6];
    const int*   src = (const int*)d_in[7];
    const int*   dst = (const int*)d_in[8];
    float* out = (float*)d_out;
    float* ws  = (float*)d_ws;
    int*   wsi = (int*)d_ws;

    int*   cnt_out  = wsi + O_CNTO;
    int*   cnt_in   = wsi + O_CNTI;
    float* norm_out = ws  + O_NRMO;
    float* norm_in  = ws  + O_NRMI;
    int*   row_st   = wsi + O_ROW;
    int*   cursor   = wsi + O_CUR;
    int*   bsum     = wsi + O_BSUM;
    int*   edge_src = wsi + O_ESRC;
    float* agg      = ws  + O_AGG;   // becomes Q in-place
    unsigned short* Kb = (unsigned short*)(ws + O_K);
    unsigned short* Vb = (unsigned short*)(ws + O_V);

    hipMemsetAsync(wsi, 0, 2 * N_NODES * sizeof(int), stream);

    k_degree<<<N_EDGES / 256, 256, 0, stream>>>(src, dst, cnt_out, cnt_in);
    k_scan1<<<NB_SCAN, 256, 0, stream>>>(cnt_in, cnt_out, row_st, bsum, norm_out, norm_in);
    k_scan2<<<1, 256, 0, stream>>>(bsum);
    k_scan3<<<NB_SCAN, 256, 0, stream>>>(row_st, bsum, cursor);
    k_scatter<<<N_EDGES / 256, 256, 0, stream>>>(src, dst, cursor, edge_src);

    k_agg_csr<<<N_NODES / 4, 256, 0, stream>>>(row_st, cnt_in, edge_src,
                                               h, norm_out, norm_in, agg);

    dim3 g_kv((N_NODES + 31) / 32, 2, 2);
    k_kv<<<g_kv, 128, 0, stream>>>(agg, WK, bK, WV, bV, Kb, Vb);
    k_q_inplace<<<(N_NODES + 31) / 32, 256, 0, stream>>>(agg, WQ, bQ);

    k_attn_csr<<<N_NODES / 4, 256, 0, stream>>>(row_st, cnt_in, edge_src,
                                                agg, Kb, Vb, out);
}

// Round 4
// 674.057 us; speedup vs baseline: 3.7091x; 1.1070x over previous
//
#include <hip/hip_runtime.h>

#define N_NODES 50000
#define N_EDGES 1600000
#define NB_SCAN 196   // ceil(50000/256)

// Workspace element offsets (4-byte units). Peak ~71.8 MB.
#define O_CNTO   0         // int[50000]
#define O_CNTI   50000     // int[50000]
#define O_NRMO   100000    // f32[50000]
#define O_NRMI   150000    // f32[50000]
#define O_ROW    200000    // int[50000]
#define O_CUR    250000    // int[50000]
#define O_BSUM   300000    // int[256]
#define O_ESRC   350000    // int[1.6M]
#define O_HB     1950000   // bf16[50000*128] = h*norm_out, 3.2M units
#define O_AGG    5150000   // f32[50000*128]; overwritten by Q in-place
#define O_KV     11550000  // bf16 interleaved K/V, 50000 rows x 512 B (6.4M units)

typedef unsigned int uint;

__device__ __forceinline__ uint f2bf2(float a, float b) {
    uint ua = __float_as_uint(a); ua = (ua + 0x7fffu + ((ua >> 16) & 1u)) >> 16;
    uint ub = __float_as_uint(b); ub = (ub + 0x7fffu + ((ub >> 16) & 1u)) >> 16;
    return ua | (ub << 16);
}

__global__ __launch_bounds__(256) void k_degree(const int* __restrict__ src,
                                                const int* __restrict__ dst,
                                                int* cnt_out, int* cnt_in) {
    int e = blockIdx.x * 256 + threadIdx.x;
    if (e < N_EDGES) {
        atomicAdd(&cnt_out[src[e]], 1);
        atomicAdd(&cnt_in[dst[e]], 1);
    }
}

__global__ __launch_bounds__(256) void k_scan1(const int* __restrict__ cnt_in,
                                               const int* __restrict__ cnt_out,
                                               int* row_start, int* bsum,
                                               float* norm_out, float* norm_in) {
    __shared__ int s[256];
    int t = threadIdx.x;
    int i = blockIdx.x * 256 + t;
    int x = (i < N_NODES) ? cnt_in[i] : 0;
    s[t] = x;
    if (i < N_NODES) {
        norm_in[i]  = rsqrtf(fmaxf((float)x, 1.0f));
        norm_out[i] = rsqrtf(fmaxf((float)cnt_out[i], 1.0f));
    }
    __syncthreads();
    for (int off = 1; off < 256; off <<= 1) {
        int v = (t >= off) ? s[t - off] : 0;
        __syncthreads();
        s[t] += v;
        __syncthreads();
    }
    if (i < N_NODES) row_start[i] = s[t] - x;
    if (t == 255) bsum[blockIdx.x] = s[255];
}

__global__ __launch_bounds__(256) void k_scan2(int* bsum) {
    __shared__ int s[256];
    int t = threadIdx.x;
    int x = (t < NB_SCAN) ? bsum[t] : 0;
    s[t] = x;
    __syncthreads();
    for (int off = 1; off < 256; off <<= 1) {
        int v = (t >= off) ? s[t - off] : 0;
        __syncthreads();
        s[t] += v;
        __syncthreads();
    }
    if (t < NB_SCAN) bsum[t] = s[t] - x;
}

__global__ __launch_bounds__(256) void k_scan3(int* row_start, const int* __restrict__ bsum,
                                               int* cursor) {
    int i = blockIdx.x * 256 + threadIdx.x;
    if (i < N_NODES) {
        int r = row_start[i] + bsum[blockIdx.x];
        row_start[i] = r;
        cursor[i] = r;
    }
}

__global__ __launch_bounds__(256) void k_scatter(const int* __restrict__ src,
                                                 const int* __restrict__ dst,
                                                 int* cursor, int* __restrict__ edge_src) {
    int e = blockIdx.x * 256 + threadIdx.x;
    if (e < N_EDGES) {
        int pos = atomicAdd(&cursor[dst[e]], 1);
        edge_src[pos] = src[e];
    }
}

// hb[n][j] = bf16(h[n][j] * norm_out[n]); one uint (2 bf16) per thread
__global__ __launch_bounds__(256) void k_hb(const float* __restrict__ h,
                                            const float* __restrict__ norm_out,
                                            uint* __restrict__ hb) {
    int idx = blockIdx.x * 256 + threadIdx.x;   // [0, N*64)
    if (idx < N_NODES * 64) {
        int n = idx >> 6;
        float no = norm_out[n];
        float2 hv = *(const float2*)(h + ((size_t)idx << 1));
        hb[idx] = f2bf2(hv.x * no, hv.y * no);
    }
}

// agg[n] = norm_in[n] * sum_{e: dst=n} hb[src_e]   (bf16 gather, 256 B/row)
// one wave per node, lane owns dims [2*lane, 2*lane+1], unrolled x4
__global__ __launch_bounds__(256) void k_agg_csr(
    const int* __restrict__ row_start, const int* __restrict__ cnt_in,
    const int* __restrict__ edge_src,
    const uint* __restrict__ hb, const float* __restrict__ norm_in,
    float* __restrict__ agg)
{
    int n = blockIdx.x * 4 + (threadIdx.x >> 6);
    int lane = threadIdx.x & 63;
    int beg = row_start[n], end = beg + cnt_in[n];
    float ax = 0.f, ay = 0.f;
    int i = beg;
    for (; i + 4 <= end; i += 4) {
        int s0 = edge_src[i], s1 = edge_src[i + 1];
        int s2 = edge_src[i + 2], s3 = edge_src[i + 3];
        uint u0 = hb[((size_t)s0 << 6) + lane];
        uint u1 = hb[((size_t)s1 << 6) + lane];
        uint u2 = hb[((size_t)s2 << 6) + lane];
        uint u3 = hb[((size_t)s3 << 6) + lane];
        ax += __uint_as_float(u0 << 16) + __uint_as_float(u1 << 16)
            + __uint_as_float(u2 << 16) + __uint_as_float(u3 << 16);
        ay += __uint_as_float(u0 & 0xffff0000u) + __uint_as_float(u1 & 0xffff0000u)
            + __uint_as_float(u2 & 0xffff0000u) + __uint_as_float(u3 & 0xffff0000u);
    }
    for (; i < end; ++i) {
        int s = edge_src[i];
        uint u = hb[((size_t)s << 6) + lane];
        ax += __uint_as_float(u << 16);
        ay += __uint_as_float(u & 0xffff0000u);
    }
    float ni = norm_in[n];
    float2 o; o.x = ax * ni; o.y = ay * ni;
    *(float2*)(agg + ((size_t)n << 7) + (lane << 1)) = o;
}

// K,V GEMM -> interleaved bf16 KV buffer.
// KV row = 128 uints: uint index 2j   = K dims [2j,2j+1]
//                     uint index 2j+1 = V dims [2j,2j+1]
__global__ __launch_bounds__(128) void k_kv(
    const float* __restrict__ agg,
    const float* __restrict__ WK, const float* __restrict__ bK,
    const float* __restrict__ WV, const float* __restrict__ bV,
    uint* __restrict__ kv)
{
    const int isV = blockIdx.y;
    const float* W    = isV ? WV : WK;
    const float* bias = isV ? bV : bK;
    const int row0 = blockIdx.x * 32;
    const int col0 = blockIdx.z * 64;

    __shared__ float sW[128][64];
    __shared__ float sA[128][36];

    const int t = threadIdx.x;
    {
        const float* Wp = W + col0;
        for (int i = t; i < 128 * 16; i += 128) {
            int k = i >> 4, c4 = (i & 15) << 2;
            *(float4*)(&sW[k][c4]) = *(const float4*)(Wp + k * 128 + c4);
        }
        for (int i = t; i < 32 * 32; i += 128) {
            int r = i >> 5, k4 = (i & 31) << 2;
            int row = row0 + r;
            float4 a = make_float4(0.f, 0.f, 0.f, 0.f);
            if (row < N_NODES) a = *(const float4*)(agg + (size_t)row * 128 + k4);
            sA[k4 + 0][r] = a.x; sA[k4 + 1][r] = a.y;
            sA[k4 + 2][r] = a.z; sA[k4 + 3][r] = a.w;
        }
    }
    __syncthreads();

    const int rq = (t & 7) << 2;
    const int cq = (t >> 3) << 2;
    float acc[4][4] = {};
    for (int k = 0; k < 128; ++k) {
        float4 a = *(const float4*)(&sA[k][rq]);
        float4 w = *(const float4*)(&sW[k][cq]);
        acc[0][0] += a.x * w.x; acc[0][1] += a.x * w.y; acc[0][2] += a.x * w.z; acc[0][3] += a.x * w.w;
        acc[1][0] += a.y * w.x; acc[1][1] += a.y * w.y; acc[1][2] += a.y * w.z; acc[1][3] += a.y * w.w;
        acc[2][0] += a.z * w.x; acc[2][1] += a.z * w.y; acc[2][2] += a.z * w.z; acc[2][3] += a.z * w.w;
        acc[3][0] += a.w * w.x; acc[3][1] += a.w * w.y; acc[3][2] += a.w * w.z; acc[3][3] += a.w * w.w;
    }

    float4 bv = *(const float4*)(bias + col0 + cq);
    const int c = col0 + cq;             // column of first element (even)
    for (int i = 0; i < 4; ++i) {
        int row = row0 + rq + i;
        if (row < N_NODES) {
            float ox = fmaxf(acc[i][0] + bv.x, 0.f);
            float oy = fmaxf(acc[i][1] + bv.y, 0.f);
            float oz = fmaxf(acc[i][2] + bv.z, 0.f);
            float ow = fmaxf(acc[i][3] + bv.w, 0.f);
            uint* o = kv + ((size_t)row << 7) + c + isV;
            o[0] = f2bf2(ox, oy);        // pair (c/2)   -> uint index c+isV
            o[2] = f2bf2(oz, ow);        // pair (c/2+1) -> uint index c+2+isV
        }
    }
}

// Q GEMM in-place over agg
__global__ __launch_bounds__(256) void k_q_inplace(
    float* __restrict__ agg, const float* __restrict__ WQ,
    const float* __restrict__ bQ)
{
    const int row0 = blockIdx.x * 32;
    __shared__ float sA[128][36];
    __shared__ float sW[32][128];

    const int t = threadIdx.x;
    for (int i = t; i < 32 * 32; i += 256) {
        int r = i >> 5, k4 = (i & 31) << 2;
        int row = row0 + r;
        float4 a = make_float4(0.f, 0.f, 0.f, 0.f);
        if (row < N_NODES) a = *(const float4*)(agg + (size_t)row * 128 + k4);
        sA[k4 + 0][r] = a.x; sA[k4 + 1][r] = a.y;
        sA[k4 + 2][r] = a.z; sA[k4 + 3][r] = a.w;
    }

    const int rq = (t & 7) << 2;
    const int cq = (t >> 3) << 2;
    float acc[4][4] = {};

    for (int kc = 0; kc < 128; kc += 32) {
        __syncthreads();
        for (int i = t; i < 1024; i += 256) {
            int k = i >> 5, c4 = (i & 31) << 2;
            *(float4*)(&sW[k][c4]) = *(const float4*)(WQ + (size_t)(kc + k) * 128 + c4);
        }
        __syncthreads();
        for (int kk = 0; kk < 32; ++kk) {
            float4 a = *(const float4*)(&sA[kc + kk][rq]);
            float4 w = *(const float4*)(&sW[kk][cq]);
            acc[0][0] += a.x * w.x; acc[0][1] += a.x * w.y; acc[0][2] += a.x * w.z; acc[0][3] += a.x * w.w;
            acc[1][0] += a.y * w.x; acc[1][1] += a.y * w.y; acc[1][2] += a.y * w.z; acc[1][3] += a.y * w.w;
            acc[2][0] += a.z * w.x; acc[2][1] += a.z * w.y; acc[2][2] += a.z * w.z; acc[2][3] += a.z * w.w;
            acc[3][0] += a.w * w.x; acc[3][1] += a.w * w.y; acc[3][2] += a.w * w.z; acc[3][3] += a.w * w.w;
        }
    }

    float4 bv = *(const float4*)(bQ + cq);
    for (int i = 0; i < 4; ++i) {
        int row = row0 + rq + i;
        if (row < N_NODES) {
            float4 o;
            o.x = fmaxf(acc[i][0] + bv.x, 0.f);
            o.y = fmaxf(acc[i][1] + bv.y, 0.f);
            o.z = fmaxf(acc[i][2] + bv.z, 0.f);
            o.w = fmaxf(acc[i][3] + bv.w, 0.f);
            *(float4*)(agg + (size_t)row * 128 + cq) = o;
        }
    }
}

__device__ __forceinline__ void attn_step(uint2 kvp, float qx, float qy,
                                          float& ax, float& ay, float& zacc) {
    float p = __uint_as_float(kvp.x << 16) * qx
            + __uint_as_float(kvp.x & 0xffff0000u) * qy;
    p += __shfl_xor(p, 1);
    p += __shfl_xor(p, 2);
    p += __shfl_xor(p, 4);
    float sc = __expf(fminf(fmaxf(p * 0.25f, -10.f), 10.f));
    ax += __uint_as_float(kvp.y << 16) * sc;
    ay += __uint_as_float(kvp.y & 0xffff0000u) * sc;
    zacc += sc;
}

// Attention gather over interleaved KV; one uint2 per edge per lane; unroll x4
__global__ __launch_bounds__(256) void k_attn_csr(
    const int* __restrict__ row_start, const int* __restrict__ cnt_in,
    const int* __restrict__ edge_src,
    const float* __restrict__ Q, const uint* __restrict__ kv,
    float* __restrict__ out)
{
    int n = blockIdx.x * 4 + (threadIdx.x >> 6);
    int lane = threadIdx.x & 63;
    int beg = row_start[n], end = beg + cnt_in[n];

    float2 q2 = *(const float2*)(Q + ((size_t)n << 7) + (lane << 1));
    float ax = 0.f, ay = 0.f, zacc = 0.f;

    int i = beg;
    for (; i + 4 <= end; i += 4) {
        int s0 = edge_src[i], s1 = edge_src[i + 1];
        int s2 = edge_src[i + 2], s3 = edge_src[i + 3];
        uint2 p0 = *(const uint2*)(kv + ((size_t)s0 << 7) + (lane << 1));
        uint2 p1 = *(const uint2*)(kv + ((size_t)s1 << 7) + (lane << 1));
        uint2 p2 = *(const uint2*)(kv + ((size_t)s2 << 7) + (lane << 1));
        uint2 p3 = *(const uint2*)(kv + ((size_t)s3 << 7) + (lane << 1));
        attn_step(p0, q2.x, q2.y, ax, ay, zacc);
        attn_step(p1, q2.x, q2.y, ax, ay, zacc);
        attn_step(p2, q2.x, q2.y, ax, ay, zacc);
        attn_step(p3, q2.x, q2.y, ax, ay, zacc);
    }
    for (; i < end; ++i) {
        int s = edge_src[i];
        uint2 p = *(const uint2*)(kv + ((size_t)s << 7) + (lane << 1));
        attn_step(p, q2.x, q2.y, ax, ay, zacc);
    }

    float inv = 1.0f / (zacc + 1e-6f);
    float2 o; o.x = ax * inv; o.y = ay * inv;
    *(float2*)(out + ((size_t)n << 7) + (lane << 1)) = o;
}

extern "C" void kernel_launch(void* const* d_in, const int* in_sizes, int n_in,
                              void* d_out, int out_size, void* d_ws, size_t ws_size,
                              hipStream_t stream) {
    const float* h   = (const float*)d_in[0];
    const float* WQ  = (const float*)d_in[1];
    const float* bQ  = (const float*)d_in[2];
    const float* WK  = (const float*)d_in[3];
    const float* bK  = (const float*)d_in[4];
    const float* WV  = (const float*)d_in[5];
    const float* bV  = (const float*)d_in[6];
    const int*   src = (const int*)d_in[7];
    const int*   dst = (const int*)d_in[8];
    float* out = (float*)d_out;
    float* ws  = (float*)d_ws;
    int*   wsi = (int*)d_ws;

    int*   cnt_out  = wsi + O_CNTO;
    int*   cnt_in   = wsi + O_CNTI;
    float* norm_out = ws  + O_NRMO;
    float* norm_in  = ws  + O_NRMI;
    int*   row_st   = wsi + O_ROW;
    int*   cursor   = wsi + O_CUR;
    int*   bsum     = wsi + O_BSUM;
    int*   edge_src = wsi + O_ESRC;
    uint*  hb       = (uint*)(ws + O_HB);
    float* agg      = ws  + O_AGG;   // becomes Q in-place
    uint*  kv       = (uint*)(ws + O_KV);

    hipMemsetAsync(wsi, 0, 2 * N_NODES * sizeof(int), stream);

    k_degree<<<N_EDGES / 256, 256, 0, stream>>>(src, dst, cnt_out, cnt_in);
    k_scan1<<<NB_SCAN, 256, 0, stream>>>(cnt_in, cnt_out, row_st, bsum, norm_out, norm_in);
    k_scan2<<<1, 256, 0, stream>>>(bsum);
    k_scan3<<<NB_SCAN, 256, 0, stream>>>(row_st, bsum, cursor);
    k_scatter<<<N_EDGES / 256, 256, 0, stream>>>(src, dst, cursor, edge_src);
    k_hb<<<(N_NODES * 64 + 255) / 256, 256, 0, stream>>>(h, norm_out, hb);

    k_agg_csr<<<N_NODES / 4, 256, 0, stream>>>(row_st, cnt_in, edge_src,
                                               hb, norm_in, agg);

    dim3 g_kv((N_NODES + 31) / 32, 2, 2);
    k_kv<<<g_kv, 128, 0, stream>>>(agg, WK, bK, WV, bV, kv);
    k_q_inplace<<<(N_NODES + 31) / 32, 256, 0, stream>>>(agg, WQ, bQ);

    k_attn_csr<<<N_NODES / 4, 256, 0, stream>>>(row_st, cnt_in, edge_src,
                                                agg, kv, out);
}